// Round 2
// baseline (137.925 us; speedup 1.0000x reference)
//
#include <hip/hip_runtime.h>
#include <cstdint>
#include <cstddef>

// Problem geometry (fixed by reference setup_inputs):
//   h: (64, 512, 32, 32) fp32;  chw = 512*32*32 = 2^19
//   k0 = int(0.1 * chw) = 52428; rank (ascending, 0-indexed) = chw-1-k0 = 471859
//   out = h * (|h| >= cutoff ? 1.0 : (1 - tau))
#define CHW 524288
#define F4_PER_SAMPLE (CHW / 4)            // 131072
#define BLOCKS_PER_SAMPLE 64
#define F4_PER_BLOCK (F4_PER_SAMPLE / BLOCKS_PER_SAMPLE)  // 2048
#define NTHREADS 256
#define F4_PER_THREAD (F4_PER_BLOCK / NTHREADS)           // 8
#define NB12 4096                           // 12-bit histogram
#define NB7  128                            // final 7-bit histogram

__device__ __forceinline__ unsigned int akey(float x) {
    return __float_as_uint(x) & 0x7FFFFFFFu;   // monotonic key for |x|
}

// ---------------- Pass 1: histogram of top 12 bits (bits 30:19) ----------------
__global__ __launch_bounds__(NTHREADS) void hist_pass1(const float4* __restrict__ h,
                                                       unsigned int* __restrict__ hist) {
    __shared__ unsigned int lh[NB12];
    const int t = threadIdx.x;
    for (int i = t; i < NB12; i += NTHREADS) lh[i] = 0;
    __syncthreads();

    const int n = blockIdx.x >> 6;          // /BLOCKS_PER_SAMPLE
    const int chunk = blockIdx.x & 63;
    const float4* p = h + (size_t)n * F4_PER_SAMPLE + (size_t)chunk * F4_PER_BLOCK;
#pragma unroll
    for (int k = 0; k < F4_PER_THREAD; ++k) {
        float4 v = p[k * NTHREADS + t];
        atomicAdd(&lh[akey(v.x) >> 19], 1u);
        atomicAdd(&lh[akey(v.y) >> 19], 1u);
        atomicAdd(&lh[akey(v.z) >> 19], 1u);
        atomicAdd(&lh[akey(v.w) >> 19], 1u);
    }
    __syncthreads();

    unsigned int* gh = hist + (size_t)n * NB12;
    for (int i = t; i < NB12; i += NTHREADS) {
        unsigned int v = lh[i];
        if (v) atomicAdd(&gh[i], v);
    }
}

// ---------------- Pass 2: among elements with top12 == b1, histogram bits 18:7 ----------------
__global__ __launch_bounds__(NTHREADS) void hist_pass2(const float4* __restrict__ h,
                                                       const unsigned int* __restrict__ state_bits,
                                                       unsigned int* __restrict__ hist) {
    __shared__ unsigned int lh[NB12];
    const int t = threadIdx.x;
    for (int i = t; i < NB12; i += NTHREADS) lh[i] = 0;
    __syncthreads();

    const int n = blockIdx.x >> 6;
    const int chunk = blockIdx.x & 63;
    const unsigned int b1 = state_bits[n];
    const float4* p = h + (size_t)n * F4_PER_SAMPLE + (size_t)chunk * F4_PER_BLOCK;
#pragma unroll
    for (int k = 0; k < F4_PER_THREAD; ++k) {
        float4 v = p[k * NTHREADS + t];
        unsigned int ka = akey(v.x), kb = akey(v.y), kc = akey(v.z), kd = akey(v.w);
        if ((ka >> 19) == b1) atomicAdd(&lh[(ka >> 7) & 0xFFFu], 1u);
        if ((kb >> 19) == b1) atomicAdd(&lh[(kb >> 7) & 0xFFFu], 1u);
        if ((kc >> 19) == b1) atomicAdd(&lh[(kc >> 7) & 0xFFFu], 1u);
        if ((kd >> 19) == b1) atomicAdd(&lh[(kd >> 7) & 0xFFFu], 1u);
    }
    __syncthreads();

    unsigned int* gh = hist + (size_t)n * NB12;
    for (int i = t; i < NB12; i += NTHREADS) {
        unsigned int v = lh[i];
        if (v) atomicAdd(&gh[i], v);
    }
}

// ---------------- Pass 3: among elements with top24 == p24, histogram bits 6:0 ----------------
__global__ __launch_bounds__(NTHREADS) void hist_pass3(const float4* __restrict__ h,
                                                       const unsigned int* __restrict__ state_bits,
                                                       unsigned int* __restrict__ hist) {
    __shared__ unsigned int lh[NB7];
    const int t = threadIdx.x;
    for (int i = t; i < NB7; i += NTHREADS) lh[i] = 0;
    __syncthreads();

    const int n = blockIdx.x >> 6;
    const int chunk = blockIdx.x & 63;
    const unsigned int p24 = state_bits[n];
    const float4* p = h + (size_t)n * F4_PER_SAMPLE + (size_t)chunk * F4_PER_BLOCK;
#pragma unroll
    for (int k = 0; k < F4_PER_THREAD; ++k) {
        float4 v = p[k * NTHREADS + t];
        unsigned int ka = akey(v.x), kb = akey(v.y), kc = akey(v.z), kd = akey(v.w);
        if ((ka >> 7) == p24) atomicAdd(&lh[ka & 0x7Fu], 1u);
        if ((kb >> 7) == p24) atomicAdd(&lh[kb & 0x7Fu], 1u);
        if ((kc >> 7) == p24) atomicAdd(&lh[kc & 0x7Fu], 1u);
        if ((kd >> 7) == p24) atomicAdd(&lh[kd & 0x7Fu], 1u);
    }
    __syncthreads();

    unsigned int* gh = hist + (size_t)n * NB7;
    for (int i = t; i < NB7; i += NTHREADS) {
        unsigned int v = lh[i];
        if (v) atomicAdd(&gh[i], v);
    }
}

// ---------------- Select: find bin containing rank r; update state ----------------
__global__ __launch_bounds__(NTHREADS) void select_pass(const unsigned int* __restrict__ hist,
                                                        int nbins, int pass,
                                                        unsigned int* __restrict__ state_bits,
                                                        unsigned int* __restrict__ state_rank,
                                                        unsigned int* __restrict__ cutoff,
                                                        unsigned int init_rank) {
    const int n = blockIdx.x;
    const int t = threadIdx.x;
    const int bpt = (nbins + NTHREADS - 1) / NTHREADS;  // 16 or 1
    const unsigned int* gh = hist + (size_t)n * nbins;

    unsigned int s = 0;
    const int b0 = t * bpt;
    for (int i = 0; i < bpt; ++i) {
        int b = b0 + i;
        if (b < nbins) s += gh[b];
    }
    __shared__ unsigned int part[NTHREADS];
    part[t] = s;
    __syncthreads();
    // inclusive Hillis-Steele scan
    for (int off = 1; off < NTHREADS; off <<= 1) {
        unsigned int v = (t >= off) ? part[t - off] : 0u;
        __syncthreads();
        part[t] += v;
        __syncthreads();
    }
    const unsigned int excl = part[t] - s;
    const unsigned int r = (pass == 0) ? init_rank : state_rank[n];
    if (s > 0 && r >= excl && r < excl + s) {
        unsigned int acc = excl;
        for (int i = 0; i < bpt; ++i) {
            int b = b0 + i;
            unsigned int c = gh[b];
            if (r < acc + c) {
                if (pass == 0) {
                    state_bits[n] = (unsigned int)b;
                    state_rank[n] = r - acc;
                } else if (pass == 1) {
                    state_bits[n] = (state_bits[n] << 12) | (unsigned int)b;
                    state_rank[n] = r - acc;
                } else {
                    cutoff[n] = (state_bits[n] << 7) | (unsigned int)b;
                }
                break;
            }
            acc += c;
        }
    }
}

// ---------------- Apply: out = h * (key >= cutoff ? 1.0 : (1 - tau)) ----------------
__global__ __launch_bounds__(NTHREADS) void apply_kernel(const float4* __restrict__ h,
                                                         const float* __restrict__ tau,
                                                         const unsigned int* __restrict__ cutoff,
                                                         float4* __restrict__ out) {
    const int n = blockIdx.x >> 6;
    const int chunk = blockIdx.x & 63;
    const unsigned int c = cutoff[n];
    const float t = tau[0];
    const float lo = 1.0f - t;
    const size_t base = (size_t)n * F4_PER_SAMPLE + (size_t)chunk * F4_PER_BLOCK;
    const int tid = threadIdx.x;
#pragma unroll
    for (int k = 0; k < F4_PER_THREAD; ++k) {
        float4 v = h[base + k * NTHREADS + tid];
        float4 o;
        o.x = v.x * ((akey(v.x) >= c) ? 1.0f : lo);
        o.y = v.y * ((akey(v.y) >= c) ? 1.0f : lo);
        o.z = v.z * ((akey(v.z) >= c) ? 1.0f : lo);
        o.w = v.w * ((akey(v.w) >= c) ? 1.0f : lo);
        out[base + k * NTHREADS + tid] = o;
    }
}

extern "C" void kernel_launch(void* const* d_in, const int* in_sizes, int n_in,
                              void* d_out, int out_size, void* d_ws, size_t ws_size,
                              hipStream_t stream) {
    const float* h = (const float*)d_in[0];
    const float* tau = (const float*)d_in[1];
    float* out = (float*)d_out;

    const int total = in_sizes[0];
    const int N = total / CHW;              // 64

    // rank of cutoff (ascending, 0-indexed), matching Python int(0.1*chw)
    const int k0 = (int)(0.1 * (double)CHW);            // 52428
    const unsigned int init_rank = (unsigned int)(CHW - 1 - k0);  // 471859

    // Workspace layout
    unsigned int* hist1 = (unsigned int*)d_ws;
    unsigned int* hist2 = hist1 + (size_t)N * NB12;
    unsigned int* hist3 = hist2 + (size_t)N * NB12;
    unsigned int* sbits = hist3 + (size_t)N * NB7;
    unsigned int* srank = sbits + N;
    unsigned int* cutk  = srank + N;
    const size_t need_bytes = (size_t)((char*)(cutk + N) - (char*)d_ws);
    (void)ws_size;

    (void)hipMemsetAsync(d_ws, 0, need_bytes, stream);

    dim3 grid((unsigned)(N * BLOCKS_PER_SAMPLE)), blk(NTHREADS);

    hist_pass1<<<grid, blk, 0, stream>>>((const float4*)h, hist1);
    select_pass<<<N, NTHREADS, 0, stream>>>(hist1, NB12, 0, sbits, srank, cutk, init_rank);
    hist_pass2<<<grid, blk, 0, stream>>>((const float4*)h, sbits, hist2);
    select_pass<<<N, NTHREADS, 0, stream>>>(hist2, NB12, 1, sbits, srank, cutk, 0u);
    hist_pass3<<<grid, blk, 0, stream>>>((const float4*)h, sbits, hist3);
    select_pass<<<N, NTHREADS, 0, stream>>>(hist3, NB7, 2, sbits, srank, cutk, 0u);
    apply_kernel<<<grid, blk, 0, stream>>>((const float4*)h, tau, cutk, (float4*)out);
}